// Round 1
// baseline (533.443 us; speedup 1.0000x reference)
//
#include <hip/hip_runtime.h>
#include <hip/hip_bf16.h>
#include <stdint.h>

#define T_TOK 32768
#define NEXP 8
#define BMT 128           // M tile
#define MT_MAX 264        // max M tiles incl. per-expert padding
#define MCAP (MT_MAX * BMT)

typedef short s16x8 __attribute__((ext_vector_type(8)));
typedef float f32x4 __attribute__((ext_vector_type(4)));

__device__ __forceinline__ void gload_lds16(const void* g, void* l) {
  typedef const __attribute__((address_space(1))) unsigned int gu32;
  typedef __attribute__((address_space(3))) unsigned int lu32;
  __builtin_amdgcn_global_load_lds((gu32*)(unsigned long long)g,
                                   (lu32*)(unsigned int)(unsigned long long)l,
                                   16, 0, 0);
}

// ---------------- routing ----------------

__global__ void k_init(int* __restrict__ meta, int* __restrict__ perm) {
  int i = blockIdx.x * blockDim.x + threadIdx.x;
  if (i < 32) meta[i] = 0;
  if (i < MCAP) perm[i] = -1;
}

__global__ void k_count(const float* __restrict__ in, int* __restrict__ ids,
                        int* __restrict__ meta) {
  int t = blockIdx.x * blockDim.x + threadIdx.x;
  if (t >= T_TOK) return;
  const float* p = in + (size_t)t * 136 + 128;
  float bv = p[0]; int best = 0;
#pragma unroll
  for (int j = 1; j < 8; ++j) { float v = p[j]; if (v > bv) { bv = v; best = j; } }
  ids[t] = best;
  atomicAdd(meta + best, 1);
}

__global__ void k_scan(int* __restrict__ meta) {
  if (threadIdx.x == 0) {
    int* counts = meta; int* offp = meta + 16;
    int acc = 0;
    for (int e = 0; e < NEXP; ++e) {
      offp[e] = acc;
      acc += ((counts[e] + BMT - 1) / BMT) * BMT;
    }
    offp[NEXP] = acc;
  }
}

__global__ void k_assign(const int* __restrict__ ids, int* __restrict__ meta,
                         int* __restrict__ rowOf, int* __restrict__ perm) {
  int t = blockIdx.x * blockDim.x + threadIdx.x;
  if (t >= T_TOK) return;
  int e = ids[t];
  int pos = atomicAdd(meta + 8 + e, 1);
  int row = meta[16 + e] + pos;   // offp[e] already final (scan done)
  rowOf[t] = row;
  perm[row] = t;
}

__global__ void k_gather(const float* __restrict__ in, const int* __restrict__ rowOf,
                         __hip_bfloat16* __restrict__ Xs) {
  int g = blockIdx.x * blockDim.x + threadIdx.x;
  if (g >= T_TOK * 32) return;
  int t = g >> 5, c = g & 31;
  int row = rowOf[t];
  f32x4 v = *(const f32x4*)(in + (size_t)t * 136 + c * 4);
  union { unsigned short u[4]; unsigned long long ll; } pk;
#pragma unroll
  for (int j = 0; j < 4; ++j) {
    __hip_bfloat16 h = __float2bfloat16(v[j]);
    pk.u[j] = *(unsigned short*)&h;
  }
  *(unsigned long long*)(Xs + (size_t)row * 128 + c * 4) = pk.ll;
}

__global__ void k_padfill(const int* __restrict__ meta, const int* __restrict__ perm,
                          unsigned int* __restrict__ Xs32) {
  int row = blockIdx.x * blockDim.x + threadIdx.x;
  if (row >= MCAP) return;
  int mtotal = meta[16 + NEXP];
  if (row < mtotal && perm[row] < 0) {
    unsigned int* p = Xs32 + (size_t)row * 64;
#pragma unroll 4
    for (int c = 0; c < 64; ++c) p[c] = 0;
  }
}

__global__ void k_w2bf(const float* __restrict__ s, unsigned long long* __restrict__ d, int n4) {
  int i = blockIdx.x * blockDim.x + threadIdx.x;
  if (i >= n4) return;
  f32x4 v = ((const f32x4*)s)[i];
  union { unsigned short u[4]; unsigned long long ll; } pk;
#pragma unroll
  for (int j = 0; j < 4; ++j) {
    __hip_bfloat16 h = __float2bfloat16(v[j]);
    pk.u[j] = *(unsigned short*)&h;
  }
  d[i] = pk.ll;
}

// ---------------- grouped GEMM ----------------
// A: [Mpad][KT] bf16 (expert-sorted rows), W: [E][NT][KT] bf16, bias: [E][NT] f32
// Y (bf16, stride NT) or Yf (f32, scattered via perm) for FINAL.

template <int BN, int BK, int KT, int NT, int WAVES_M, int WAVES_N, bool RELU, bool FINAL>
__global__ __launch_bounds__(256) void k_gemm(
    const __hip_bfloat16* __restrict__ A,
    const __hip_bfloat16* __restrict__ W,
    const float* __restrict__ bias,
    __hip_bfloat16* __restrict__ Y,
    float* __restrict__ Yf,
    const int* __restrict__ meta,
    const int* __restrict__ perm) {
  static_assert(WAVES_M * WAVES_N == 4, "256 threads = 4 waves");
  constexpr int WTM = BMT / WAVES_M;
  constexpr int WTN = BN / WAVES_N;
  constexpr int FM = WTM / 16, FN = WTN / 16;

  __shared__ __hip_bfloat16 lA[BMT * BK];
  __shared__ __hip_bfloat16 lB[BN * BK];

  const int* offp = meta + 16;
  int m0 = blockIdx.x * BMT;
  int mtotal = offp[NEXP];
  if (m0 >= mtotal) return;
  int e = 0;
#pragma unroll
  for (int i = 1; i < NEXP; ++i) e += (m0 >= offp[i]) ? 1 : 0;

  int n0 = blockIdx.y * BN;
  int tid = threadIdx.x;
  int lane = tid & 63;
  int wave = tid >> 6;
  int wm0 = (wave / WAVES_N) * WTM;
  int wn0 = (wave % WAVES_N) * WTN;

  f32x4 acc[FM][FN];
#pragma unroll
  for (int i = 0; i < FM; ++i)
#pragma unroll
    for (int j = 0; j < FN; ++j) {
      acc[i][j][0] = 0.f; acc[i][j][1] = 0.f; acc[i][j][2] = 0.f; acc[i][j][3] = 0.f;
    }

  const __hip_bfloat16* Wb = W + ((size_t)e * NT + n0) * KT;
  constexpr int CPR = BK / 8;                 // 16B chunks per row
  constexpr int NA = (BMT * BK / 8) / 256;    // A-stage issues per thread
  constexpr int NB = (BN * BK / 8) / 256;     // B-stage issues per thread

  for (int kt = 0; kt < KT; kt += BK) {
#pragma unroll
    for (int i = 0; i < NA; ++i) {
      int c = i * 256 + tid;
      int r = c / CPR, kc = c % CPR;
      gload_lds16(A + (size_t)(m0 + r) * KT + kt + kc * 8, (char*)lA + c * 16);
    }
#pragma unroll
    for (int i = 0; i < NB; ++i) {
      int c = i * 256 + tid;
      int r = c / CPR, kc = c % CPR;
      gload_lds16(Wb + (size_t)r * KT + kt + kc * 8, (char*)lB + c * 16);
    }
    __syncthreads();
#pragma unroll
    for (int kk = 0; kk < BK; kk += 32) {
      int ko = kk + ((lane >> 4) << 3);
      s16x8 af[FM], bfr[FN];
#pragma unroll
      for (int i = 0; i < FM; ++i)
        af[i] = *(const s16x8*)(lA + (wm0 + i * 16 + (lane & 15)) * BK + ko);
#pragma unroll
      for (int j = 0; j < FN; ++j)
        bfr[j] = *(const s16x8*)(lB + (wn0 + j * 16 + (lane & 15)) * BK + ko);
#pragma unroll
      for (int i = 0; i < FM; ++i)
#pragma unroll
        for (int j = 0; j < FN; ++j)
          acc[i][j] = __builtin_amdgcn_mfma_f32_16x16x32_bf16(af[i], bfr[j], acc[i][j], 0, 0, 0);
    }
    __syncthreads();
  }

  const float* bp = bias + (size_t)e * NT + n0;
#pragma unroll
  for (int j = 0; j < FN; ++j) {
    int nc = wn0 + j * 16 + (lane & 15);
    float bv = bp[nc];
#pragma unroll
    for (int i = 0; i < FM; ++i) {
#pragma unroll
      for (int r = 0; r < 4; ++r) {
        int mr = wm0 + i * 16 + ((lane >> 4) << 2) + r;
        float v = acc[i][j][r] + bv;
        if (RELU) v = fmaxf(v, 0.f);
        if (FINAL) {
          int tok = perm[m0 + mr];
          if (tok >= 0) Yf[(size_t)tok * NT + n0 + nc] = v;
        } else {
          Y[(size_t)(m0 + mr) * NT + n0 + nc] = __float2bfloat16(v);
        }
      }
    }
  }
}

// ---------------- host ----------------

extern "C" void kernel_launch(void* const* d_in, const int* in_sizes, int n_in,
                              void* d_out, int out_size, void* d_ws, size_t ws_size,
                              hipStream_t stream) {
  const float* input = (const float*)d_in[0];
  const float* Wf[7]; const float* Bf[7];
  for (int i = 0; i < 7; ++i) { Wf[i] = (const float*)d_in[1 + 2 * i]; Bf[i] = (const float*)d_in[2 + 2 * i]; }
  float* out = (float*)d_out;

  static const int NN[7] = {512, 512, 512, 512, 512, 256, 32};
  static const int KK[7] = {128, 512, 512, 512, 512, 512, 256};

  char* ws = (char*)d_ws;
  size_t off = 0;
  auto carve = [&](size_t bytes) {
    void* p = ws + off;
    off = (off + bytes + 255) & ~(size_t)255;
    return p;
  };
  int* meta  = (int*)carve(128);                       // counts[8], cursors[8], offp[9]
  int* ids   = (int*)carve(sizeof(int) * T_TOK);
  int* rowOf = (int*)carve(sizeof(int) * T_TOK);
  int* perm  = (int*)carve(sizeof(int) * MCAP);
  __hip_bfloat16* Xs   = (__hip_bfloat16*)carve((size_t)MCAP * 128 * 2);
  __hip_bfloat16* actA = (__hip_bfloat16*)carve((size_t)MCAP * 512 * 2);
  __hip_bfloat16* actB = (__hip_bfloat16*)carve((size_t)MCAP * 512 * 2);
  __hip_bfloat16* Wb[7];
  for (int i = 0; i < 7; ++i) Wb[i] = (__hip_bfloat16*)carve((size_t)NEXP * NN[i] * KK[i] * 2);

  k_init<<<dim3((MCAP + 255) / 256), 256, 0, stream>>>(meta, perm);
  for (int i = 0; i < 7; ++i) {
    int n4 = NEXP * NN[i] * KK[i] / 4;
    k_w2bf<<<dim3((n4 + 255) / 256), 256, 0, stream>>>(Wf[i], (unsigned long long*)Wb[i], n4);
  }
  k_count<<<dim3(T_TOK / 256), 256, 0, stream>>>(input, ids, meta);
  k_scan<<<dim3(1), 64, 0, stream>>>(meta);
  k_assign<<<dim3(T_TOK / 256), 256, 0, stream>>>(ids, meta, rowOf, perm);
  k_gather<<<dim3(T_TOK * 32 / 256), 256, 0, stream>>>(input, rowOf, Xs);
  k_padfill<<<dim3((MCAP + 255) / 256), 256, 0, stream>>>(meta, perm, (unsigned int*)Xs);

  dim3 blk(256);
  k_gemm<128, 64, 128, 512, 2, 2, true,  false><<<dim3(MT_MAX, 4), blk, 0, stream>>>(Xs,   Wb[0], Bf[0], actA, nullptr, meta, perm);
  k_gemm<128, 64, 512, 512, 2, 2, true,  false><<<dim3(MT_MAX, 4), blk, 0, stream>>>(actA, Wb[1], Bf[1], actB, nullptr, meta, perm);
  k_gemm<128, 64, 512, 512, 2, 2, false, false><<<dim3(MT_MAX, 4), blk, 0, stream>>>(actB, Wb[2], Bf[2], actA, nullptr, meta, perm);
  k_gemm<128, 64, 512, 512, 2, 2, true,  false><<<dim3(MT_MAX, 4), blk, 0, stream>>>(actA, Wb[3], Bf[3], actB, nullptr, meta, perm);
  k_gemm<128, 64, 512, 512, 2, 2, true,  false><<<dim3(MT_MAX, 4), blk, 0, stream>>>(actB, Wb[4], Bf[4], actA, nullptr, meta, perm);
  k_gemm<128, 64, 512, 256, 2, 2, false, false><<<dim3(MT_MAX, 2), blk, 0, stream>>>(actA, Wb[5], Bf[5], actB, nullptr, meta, perm);
  k_gemm< 32, 64, 256,  32, 4, 1, false, true ><<<dim3(MT_MAX, 1), blk, 0, stream>>>(actB, Wb[6], Bf[6], nullptr, out, meta, perm);
}

// Round 2
// 268.806 us; speedup vs baseline: 1.9845x; 1.9845x over previous
//
#include <hip/hip_runtime.h>
#include <hip/hip_bf16.h>
#include <stdint.h>

#define T_TOK 32768
#define NEXP 8
#define BMT 128           // M tile
#define MT_MAX 264        // max M tiles incl. per-expert padding
#define MCAP (MT_MAX * BMT)
#define NBLK (T_TOK / 256) // routing blocks

typedef short s16x8 __attribute__((ext_vector_type(8)));
typedef float f32x4 __attribute__((ext_vector_type(4)));

__device__ __forceinline__ void gload_lds16(const void* g, void* l) {
  typedef const __attribute__((address_space(1))) unsigned int gu32;
  typedef __attribute__((address_space(3))) unsigned int lu32;
  __builtin_amdgcn_global_load_lds((gu32*)(unsigned long long)g,
                                   (lu32*)(unsigned int)(unsigned long long)l,
                                   16, 0, 0);
}

// ---------------- routing (atomic-free at device scope) ----------------

__global__ void k_init(int* __restrict__ perm) {
  int i = blockIdx.x * blockDim.x + threadIdx.x;
  if (i < MCAP) perm[i] = -1;
}

// per-block LDS histogram -> blockHist[b][8]; also ids[t]
__global__ void k_hist(const float* __restrict__ in, int* __restrict__ ids,
                       int* __restrict__ blockHist) {
  __shared__ int h[NEXP];
  int tid = threadIdx.x;
  if (tid < NEXP) h[tid] = 0;
  __syncthreads();
  int t = blockIdx.x * 256 + tid;
  const float* p = in + (size_t)t * 136 + 128;
  float bv = p[0]; int best = 0;
#pragma unroll
  for (int j = 1; j < 8; ++j) { float v = p[j]; if (v > bv) { bv = v; best = j; } }
  ids[t] = best;
  atomicAdd(&h[best], 1);   // LDS atomic — cheap
  __syncthreads();
  if (tid < NEXP) blockHist[blockIdx.x * NEXP + tid] = h[tid];
}

// single block: per-expert exclusive prefix over blocks + padded expert offsets
__global__ void k_scan(const int* __restrict__ blockHist, int* __restrict__ blockBase,
                       int* __restrict__ meta) {
  __shared__ int cnt[NEXP];
  int e = threadIdx.x;
  if (e < NEXP) {
    int acc = 0;
    for (int b = 0; b < NBLK; ++b) {
      blockBase[b * NEXP + e] = acc;
      acc += blockHist[b * NEXP + e];
    }
    cnt[e] = acc;
  }
  __syncthreads();
  if (e == 0) {
    int acc = 0;
    for (int i = 0; i < NEXP; ++i) {
      meta[16 + i] = acc;
      acc += ((cnt[i] + BMT - 1) / BMT) * BMT;
    }
    meta[16 + NEXP] = acc;
  }
  __syncthreads();
  if (e < NEXP) {
    int o = meta[16 + e];
    for (int b = 0; b < NBLK; ++b) blockBase[b * NEXP + e] += o;
  }
}

// rank within block via LDS atomics seeded from blockBase
__global__ void k_assign(const int* __restrict__ ids, const int* __restrict__ blockBase,
                         int* __restrict__ rowOf, int* __restrict__ perm) {
  __shared__ int cur[NEXP];
  int tid = threadIdx.x;
  if (tid < NEXP) cur[tid] = blockBase[blockIdx.x * NEXP + tid];
  __syncthreads();
  int t = blockIdx.x * 256 + tid;
  int e = ids[t];
  int row = atomicAdd(&cur[e], 1);   // LDS atomic — cheap
  rowOf[t] = row;
  perm[row] = t;
}

__global__ void k_gather(const float* __restrict__ in, const int* __restrict__ rowOf,
                         __hip_bfloat16* __restrict__ Xs) {
  int g = blockIdx.x * blockDim.x + threadIdx.x;
  if (g >= T_TOK * 32) return;
  int t = g >> 5, c = g & 31;
  int row = rowOf[t];
  f32x4 v = *(const f32x4*)(in + (size_t)t * 136 + c * 4);
  union { unsigned short u[4]; unsigned long long ll; } pk;
#pragma unroll
  for (int j = 0; j < 4; ++j) {
    __hip_bfloat16 h = __float2bfloat16(v[j]);
    pk.u[j] = *(unsigned short*)&h;
  }
  *(unsigned long long*)(Xs + (size_t)row * 128 + c * 4) = pk.ll;
}

__global__ void k_padfill(const int* __restrict__ meta, const int* __restrict__ perm,
                          unsigned int* __restrict__ Xs32) {
  int row = blockIdx.x * blockDim.x + threadIdx.x;
  if (row >= MCAP) return;
  int mtotal = meta[16 + NEXP];
  if (row < mtotal && perm[row] < 0) {
    unsigned int* p = Xs32 + (size_t)row * 64;
#pragma unroll 4
    for (int c = 0; c < 64; ++c) p[c] = 0;
  }
}

__global__ void k_w2bf(const float* __restrict__ s, unsigned long long* __restrict__ d, int n4) {
  int i = blockIdx.x * blockDim.x + threadIdx.x;
  if (i >= n4) return;
  f32x4 v = ((const f32x4*)s)[i];
  union { unsigned short u[4]; unsigned long long ll; } pk;
#pragma unroll
  for (int j = 0; j < 4; ++j) {
    __hip_bfloat16 h = __float2bfloat16(v[j]);
    pk.u[j] = *(unsigned short*)&h;
  }
  d[i] = pk.ll;
}

// ---------------- grouped GEMM ----------------
// A: [Mpad][KT] bf16 (expert-sorted rows), W: [E][NT][KT] bf16, bias: [E][NT] f32
// Y (bf16, stride NT) or Yf (f32, scattered via perm) for FINAL.

template <int BN, int BK, int KT, int NT, int WAVES_M, int WAVES_N, bool RELU, bool FINAL>
__global__ __launch_bounds__(256) void k_gemm(
    const __hip_bfloat16* __restrict__ A,
    const __hip_bfloat16* __restrict__ W,
    const float* __restrict__ bias,
    __hip_bfloat16* __restrict__ Y,
    float* __restrict__ Yf,
    const int* __restrict__ meta,
    const int* __restrict__ perm) {
  static_assert(WAVES_M * WAVES_N == 4, "256 threads = 4 waves");
  constexpr int WTM = BMT / WAVES_M;
  constexpr int WTN = BN / WAVES_N;
  constexpr int FM = WTM / 16, FN = WTN / 16;

  __shared__ __hip_bfloat16 lA[BMT * BK];
  __shared__ __hip_bfloat16 lB[BN * BK];

  const int* offp = meta + 16;
  int m0 = blockIdx.x * BMT;
  int mtotal = offp[NEXP];
  if (m0 >= mtotal) return;
  int e = 0;
#pragma unroll
  for (int i = 1; i < NEXP; ++i) e += (m0 >= offp[i]) ? 1 : 0;

  int n0 = blockIdx.y * BN;
  int tid = threadIdx.x;
  int lane = tid & 63;
  int wave = tid >> 6;
  int wm0 = (wave / WAVES_N) * WTM;
  int wn0 = (wave % WAVES_N) * WTN;

  f32x4 acc[FM][FN];
#pragma unroll
  for (int i = 0; i < FM; ++i)
#pragma unroll
    for (int j = 0; j < FN; ++j) {
      acc[i][j][0] = 0.f; acc[i][j][1] = 0.f; acc[i][j][2] = 0.f; acc[i][j][3] = 0.f;
    }

  const __hip_bfloat16* Wb = W + ((size_t)e * NT + n0) * KT;
  constexpr int CPR = BK / 8;                 // 16B chunks per row
  constexpr int NA = (BMT * BK / 8) / 256;    // A-stage issues per thread
  constexpr int NB = (BN * BK / 8) / 256;     // B-stage issues per thread

  for (int kt = 0; kt < KT; kt += BK) {
#pragma unroll
    for (int i = 0; i < NA; ++i) {
      int c = i * 256 + tid;
      int r = c / CPR, kc = c % CPR;
      gload_lds16(A + (size_t)(m0 + r) * KT + kt + kc * 8, (char*)lA + c * 16);
    }
#pragma unroll
    for (int i = 0; i < NB; ++i) {
      int c = i * 256 + tid;
      int r = c / CPR, kc = c % CPR;
      gload_lds16(Wb + (size_t)r * KT + kt + kc * 8, (char*)lB + c * 16);
    }
    __syncthreads();
#pragma unroll
    for (int kk = 0; kk < BK; kk += 32) {
      int ko = kk + ((lane >> 4) << 3);
      s16x8 af[FM], bfr[FN];
#pragma unroll
      for (int i = 0; i < FM; ++i)
        af[i] = *(const s16x8*)(lA + (wm0 + i * 16 + (lane & 15)) * BK + ko);
#pragma unroll
      for (int j = 0; j < FN; ++j)
        bfr[j] = *(const s16x8*)(lB + (wn0 + j * 16 + (lane & 15)) * BK + ko);
#pragma unroll
      for (int i = 0; i < FM; ++i)
#pragma unroll
        for (int j = 0; j < FN; ++j)
          acc[i][j] = __builtin_amdgcn_mfma_f32_16x16x32_bf16(af[i], bfr[j], acc[i][j], 0, 0, 0);
    }
    __syncthreads();
  }

  const float* bp = bias + (size_t)e * NT + n0;
#pragma unroll
  for (int j = 0; j < FN; ++j) {
    int nc = wn0 + j * 16 + (lane & 15);
    float bv = bp[nc];
#pragma unroll
    for (int i = 0; i < FM; ++i) {
#pragma unroll
      for (int r = 0; r < 4; ++r) {
        int mr = wm0 + i * 16 + ((lane >> 4) << 2) + r;
        float v = acc[i][j][r] + bv;
        if (RELU) v = fmaxf(v, 0.f);
        if (FINAL) {
          int tok = perm[m0 + mr];
          if (tok >= 0) Yf[(size_t)tok * NT + n0 + nc] = v;
        } else {
          Y[(size_t)(m0 + mr) * NT + n0 + nc] = __float2bfloat16(v);
        }
      }
    }
  }
}

// ---------------- host ----------------

extern "C" void kernel_launch(void* const* d_in, const int* in_sizes, int n_in,
                              void* d_out, int out_size, void* d_ws, size_t ws_size,
                              hipStream_t stream) {
  const float* input = (const float*)d_in[0];
  const float* Wf[7]; const float* Bf[7];
  for (int i = 0; i < 7; ++i) { Wf[i] = (const float*)d_in[1 + 2 * i]; Bf[i] = (const float*)d_in[2 + 2 * i]; }
  float* out = (float*)d_out;

  static const int NN[7] = {512, 512, 512, 512, 512, 256, 32};
  static const int KK[7] = {128, 512, 512, 512, 512, 512, 256};

  char* ws = (char*)d_ws;
  size_t off = 0;
  auto carve = [&](size_t bytes) {
    void* p = ws + off;
    off = (off + bytes + 255) & ~(size_t)255;
    return p;
  };
  int* meta      = (int*)carve(128);                    // offp at meta[16..24]
  int* ids       = (int*)carve(sizeof(int) * T_TOK);
  int* rowOf     = (int*)carve(sizeof(int) * T_TOK);
  int* perm      = (int*)carve(sizeof(int) * MCAP);
  int* blockHist = (int*)carve(sizeof(int) * NBLK * NEXP);
  int* blockBase = (int*)carve(sizeof(int) * NBLK * NEXP);
  __hip_bfloat16* Xs   = (__hip_bfloat16*)carve((size_t)MCAP * 128 * 2);
  __hip_bfloat16* actA = (__hip_bfloat16*)carve((size_t)MCAP * 512 * 2);
  __hip_bfloat16* actB = (__hip_bfloat16*)carve((size_t)MCAP * 512 * 2);
  __hip_bfloat16* Wb[7];
  for (int i = 0; i < 7; ++i) Wb[i] = (__hip_bfloat16*)carve((size_t)NEXP * NN[i] * KK[i] * 2);

  k_init<<<dim3((MCAP + 255) / 256), 256, 0, stream>>>(perm);
  for (int i = 0; i < 7; ++i) {
    int n4 = NEXP * NN[i] * KK[i] / 4;
    k_w2bf<<<dim3((n4 + 255) / 256), 256, 0, stream>>>(Wf[i], (unsigned long long*)Wb[i], n4);
  }
  k_hist<<<dim3(NBLK), 256, 0, stream>>>(input, ids, blockHist);
  k_scan<<<dim3(1), 64, 0, stream>>>(blockHist, blockBase, meta);
  k_assign<<<dim3(NBLK), 256, 0, stream>>>(ids, blockBase, rowOf, perm);
  k_gather<<<dim3(T_TOK * 32 / 256), 256, 0, stream>>>(input, rowOf, Xs);
  k_padfill<<<dim3((MCAP + 255) / 256), 256, 0, stream>>>(meta, perm, (unsigned int*)Xs);

  dim3 blk(256);
  k_gemm<128, 64, 128, 512, 2, 2, true,  false><<<dim3(MT_MAX, 4), blk, 0, stream>>>(Xs,   Wb[0], Bf[0], actA, nullptr, meta, perm);
  k_gemm<128, 64, 512, 512, 2, 2, true,  false><<<dim3(MT_MAX, 4), blk, 0, stream>>>(actA, Wb[1], Bf[1], actB, nullptr, meta, perm);
  k_gemm<128, 64, 512, 512, 2, 2, false, false><<<dim3(MT_MAX, 4), blk, 0, stream>>>(actB, Wb[2], Bf[2], actA, nullptr, meta, perm);
  k_gemm<128, 64, 512, 512, 2, 2, true,  false><<<dim3(MT_MAX, 4), blk, 0, stream>>>(actA, Wb[3], Bf[3], actB, nullptr, meta, perm);
  k_gemm<128, 64, 512, 512, 2, 2, true,  false><<<dim3(MT_MAX, 4), blk, 0, stream>>>(actB, Wb[4], Bf[4], actA, nullptr, meta, perm);
  k_gemm<128, 64, 512, 256, 2, 2, false, false><<<dim3(MT_MAX, 2), blk, 0, stream>>>(actA, Wb[5], Bf[5], actB, nullptr, meta, perm);
  k_gemm< 32, 64, 256,  32, 4, 1, false, true ><<<dim3(MT_MAX, 1), blk, 0, stream>>>(actB, Wb[6], Bf[6], nullptr, out, meta, perm);
}

// Round 3
// 229.699 us; speedup vs baseline: 2.3224x; 1.1703x over previous
//
#include <hip/hip_runtime.h>
#include <hip/hip_bf16.h>
#include <stdint.h>

#define T_TOK 32768
#define NEXP 8
#define BMT 128           // M tile
#define MT_MAX 264        // max M tiles incl. per-expert padding
#define MCAP (MT_MAX * BMT)
#define NBLK (T_TOK / 256) // routing blocks

typedef short s16x8 __attribute__((ext_vector_type(8)));
typedef float f32x4 __attribute__((ext_vector_type(4)));

__device__ __forceinline__ void gload_lds16(const void* g, void* l) {
  typedef const __attribute__((address_space(1))) unsigned int gu32;
  typedef __attribute__((address_space(3))) unsigned int lu32;
  __builtin_amdgcn_global_load_lds((gu32*)(unsigned long long)g,
                                   (lu32*)(unsigned int)(unsigned long long)l,
                                   16, 0, 0);
}

// ---------------- routing (atomic-free at device scope) ----------------

__global__ void k_init(int* __restrict__ perm) {
  int i = blockIdx.x * blockDim.x + threadIdx.x;
  if (i < MCAP) perm[i] = -1;
}

__global__ void k_hist(const float* __restrict__ in, int* __restrict__ ids,
                       int* __restrict__ blockHist) {
  __shared__ int h[NEXP];
  int tid = threadIdx.x;
  if (tid < NEXP) h[tid] = 0;
  __syncthreads();
  int t = blockIdx.x * 256 + tid;
  const float* p = in + (size_t)t * 136 + 128;
  float bv = p[0]; int best = 0;
#pragma unroll
  for (int j = 1; j < 8; ++j) { float v = p[j]; if (v > bv) { bv = v; best = j; } }
  ids[t] = best;
  atomicAdd(&h[best], 1);   // LDS atomic — cheap
  __syncthreads();
  if (tid < NEXP) blockHist[blockIdx.x * NEXP + tid] = h[tid];
}

__global__ void k_scan(const int* __restrict__ blockHist, int* __restrict__ blockBase,
                       int* __restrict__ meta) {
  __shared__ int cnt[NEXP];
  int e = threadIdx.x;
  if (e < NEXP) {
    int acc = 0;
    for (int b = 0; b < NBLK; ++b) {
      blockBase[b * NEXP + e] = acc;
      acc += blockHist[b * NEXP + e];
    }
    cnt[e] = acc;
  }
  __syncthreads();
  if (e == 0) {
    int acc = 0;
    for (int i = 0; i < NEXP; ++i) {
      meta[16 + i] = acc;
      acc += ((cnt[i] + BMT - 1) / BMT) * BMT;
    }
    meta[16 + NEXP] = acc;
  }
  __syncthreads();
  if (e < NEXP) {
    int o = meta[16 + e];
    for (int b = 0; b < NBLK; ++b) blockBase[b * NEXP + e] += o;
  }
}

__global__ void k_assign(const int* __restrict__ ids, const int* __restrict__ blockBase,
                         int* __restrict__ rowOf, int* __restrict__ perm) {
  __shared__ int cur[NEXP];
  int tid = threadIdx.x;
  if (tid < NEXP) cur[tid] = blockBase[blockIdx.x * NEXP + tid];
  __syncthreads();
  int t = blockIdx.x * 256 + tid;
  int e = ids[t];
  int row = atomicAdd(&cur[e], 1);   // LDS atomic — cheap
  rowOf[t] = row;
  perm[row] = t;
}

__global__ void k_gather(const float* __restrict__ in, const int* __restrict__ rowOf,
                         __hip_bfloat16* __restrict__ Xs) {
  int g = blockIdx.x * blockDim.x + threadIdx.x;
  if (g >= T_TOK * 32) return;
  int t = g >> 5, c = g & 31;
  int row = rowOf[t];
  f32x4 v = *(const f32x4*)(in + (size_t)t * 136 + c * 4);
  union { unsigned short u[4]; unsigned long long ll; } pk;
#pragma unroll
  for (int j = 0; j < 4; ++j) {
    __hip_bfloat16 h = __float2bfloat16(v[j]);
    pk.u[j] = *(unsigned short*)&h;
  }
  *(unsigned long long*)(Xs + (size_t)row * 128 + c * 4) = pk.ll;
}

__global__ void k_padfill(const int* __restrict__ meta, const int* __restrict__ perm,
                          unsigned int* __restrict__ Xs32) {
  int row = blockIdx.x * blockDim.x + threadIdx.x;
  if (row >= MCAP) return;
  int mtotal = meta[16 + NEXP];
  if (row < mtotal && perm[row] < 0) {
    unsigned int* p = Xs32 + (size_t)row * 64;
#pragma unroll 4
    for (int c = 0; c < 64; ++c) p[c] = 0;
  }
}

__global__ void k_w2bf(const float* __restrict__ s, unsigned long long* __restrict__ d, int n4) {
  int i = blockIdx.x * blockDim.x + threadIdx.x;
  if (i >= n4) return;
  f32x4 v = ((const f32x4*)s)[i];
  union { unsigned short u[4]; unsigned long long ll; } pk;
#pragma unroll
  for (int j = 0; j < 4; ++j) {
    __hip_bfloat16 h = __float2bfloat16(v[j]);
    pk.u[j] = *(unsigned short*)&h;
  }
  d[i] = pk.ll;
}

// ---------------- grouped GEMM (dbuf + counted vmcnt + XOR swizzle) ----------------
// A: [Mpad][KT] bf16 (expert-sorted rows), W: [E][NT][KT] bf16, bias: [E][NT] f32
// LDS layout is XOR-swizzled: 16B chunk kc of row r holds global chunk (kc ^ (r&7)).
// Staging keeps gload_lds dest LINEAR and pre-swizzles the GLOBAL source (m173);
// reads apply the same XOR -> 16-way bank conflict becomes 2-way (free).

template <int BN, int BK, int KT, int NT, int WAVES_M, int WAVES_N, bool RELU, bool FINAL>
__global__ __launch_bounds__(256) void k_gemm(
    const __hip_bfloat16* __restrict__ A,
    const __hip_bfloat16* __restrict__ W,
    const float* __restrict__ bias,
    __hip_bfloat16* __restrict__ Y,
    float* __restrict__ Yf,
    const int* __restrict__ meta,
    const int* __restrict__ perm) {
  static_assert(WAVES_M * WAVES_N == 4, "256 threads = 4 waves");
  constexpr int WTM = BMT / WAVES_M;
  constexpr int WTN = BN / WAVES_N;
  constexpr int FM = WTM / 16, FN = WTN / 16;
  constexpr int CPR = BK / 8;                 // 16B chunks per row (8 for BK=64)
  constexpr int NA = (BMT * BK / 8) / 256;    // A-stage issues per thread
  constexpr int NB = (BN * BK / 8) / 256;     // B-stage issues per thread
  constexpr int NLD = NA + NB;
  constexpr int NSTEP = KT / BK;

  __shared__ __hip_bfloat16 lA[2][BMT * BK];
  __shared__ __hip_bfloat16 lB[2][BN * BK];

  const int* offp = meta + 16;
  int m0 = blockIdx.x * BMT;
  int mtotal = offp[NEXP];
  if (m0 >= mtotal) return;
  int e = 0;
#pragma unroll
  for (int i = 1; i < NEXP; ++i) e += (m0 >= offp[i]) ? 1 : 0;

  int n0 = blockIdx.y * BN;
  int tid = threadIdx.x;
  int lane = tid & 63;
  int wave = tid >> 6;
  int wm0 = (wave / WAVES_N) * WTM;
  int wn0 = (wave % WAVES_N) * WTN;

  f32x4 acc[FM][FN];
#pragma unroll
  for (int i = 0; i < FM; ++i)
#pragma unroll
    for (int j = 0; j < FN; ++j) {
      acc[i][j][0] = 0.f; acc[i][j][1] = 0.f; acc[i][j][2] = 0.f; acc[i][j][3] = 0.f;
    }

  const __hip_bfloat16* Wb = W + ((size_t)e * NT + n0) * KT;

  // stage K-tile kt into buffer b; LDS dest linear, global source chunk-swizzled
  auto stage = [&](int b, int kt) {
#pragma unroll
    for (int i = 0; i < NA; ++i) {
      int c = i * 256 + tid;
      int r = c / CPR, kc = c % CPR;
      int kcs = kc ^ (r & 7);
      gload_lds16(A + (size_t)(m0 + r) * KT + kt + kcs * 8, (char*)lA[b] + c * 16);
    }
#pragma unroll
    for (int i = 0; i < NB; ++i) {
      int c = i * 256 + tid;
      int r = c / CPR, kc = c % CPR;
      int kcs = kc ^ (r & 7);
      gload_lds16(Wb + (size_t)r * KT + kt + kcs * 8, (char*)lB[b] + c * 16);
    }
  };

  stage(0, 0);
  int cur = 0;
  for (int s = 0; s < NSTEP; ++s) {
    __builtin_amdgcn_sched_barrier(0);
    if (s + 1 < NSTEP) {
      stage(cur ^ 1, (s + 1) * BK);
      asm volatile("s_waitcnt vmcnt(%0)" :: "i"(NLD) : "memory");
    } else {
      asm volatile("s_waitcnt vmcnt(0)" ::: "memory");
    }
    __builtin_amdgcn_s_barrier();
    __builtin_amdgcn_sched_barrier(0);

    __builtin_amdgcn_s_setprio(1);
#pragma unroll
    for (int kk = 0; kk < BK; kk += 32) {
      int cj = (kk >> 3) + (lane >> 4);       // 16B chunk index within row
      s16x8 af[FM], bfr[FN];
#pragma unroll
      for (int i = 0; i < FM; ++i) {
        int ar = wm0 + i * 16 + (lane & 15);
        int js = cj ^ (ar & 7);
        af[i] = *(const s16x8*)(lA[cur] + ar * BK + js * 8);
      }
#pragma unroll
      for (int j = 0; j < FN; ++j) {
        int br = wn0 + j * 16 + (lane & 15);
        int js = cj ^ (br & 7);
        bfr[j] = *(const s16x8*)(lB[cur] + br * BK + js * 8);
      }
#pragma unroll
      for (int i = 0; i < FM; ++i)
#pragma unroll
        for (int j = 0; j < FN; ++j)
          acc[i][j] = __builtin_amdgcn_mfma_f32_16x16x32_bf16(af[i], bfr[j], acc[i][j], 0, 0, 0);
    }
    __builtin_amdgcn_s_setprio(0);
    __builtin_amdgcn_sched_barrier(0);
    __builtin_amdgcn_s_barrier();
    cur ^= 1;
  }

  const float* bp = bias + (size_t)e * NT + n0;
#pragma unroll
  for (int j = 0; j < FN; ++j) {
    int nc = wn0 + j * 16 + (lane & 15);
    float bv = bp[nc];
#pragma unroll
    for (int i = 0; i < FM; ++i) {
#pragma unroll
      for (int r = 0; r < 4; ++r) {
        int mr = wm0 + i * 16 + ((lane >> 4) << 2) + r;
        float v = acc[i][j][r] + bv;
        if (RELU) v = fmaxf(v, 0.f);
        if (FINAL) {
          int tok = perm[m0 + mr];
          if (tok >= 0) Yf[(size_t)tok * NT + n0 + nc] = v;
        } else {
          Y[(size_t)(m0 + mr) * NT + n0 + nc] = __float2bfloat16(v);
        }
      }
    }
  }
}

// ---------------- host ----------------

extern "C" void kernel_launch(void* const* d_in, const int* in_sizes, int n_in,
                              void* d_out, int out_size, void* d_ws, size_t ws_size,
                              hipStream_t stream) {
  const float* input = (const float*)d_in[0];
  const float* Wf[7]; const float* Bf[7];
  for (int i = 0; i < 7; ++i) { Wf[i] = (const float*)d_in[1 + 2 * i]; Bf[i] = (const float*)d_in[2 + 2 * i]; }
  float* out = (float*)d_out;

  static const int NN[7] = {512, 512, 512, 512, 512, 256, 32};
  static const int KK[7] = {128, 512, 512, 512, 512, 512, 256};

  char* ws = (char*)d_ws;
  size_t off = 0;
  auto carve = [&](size_t bytes) {
    void* p = ws + off;
    off = (off + bytes + 255) & ~(size_t)255;
    return p;
  };
  int* meta      = (int*)carve(128);                    // offp at meta[16..24]
  int* ids       = (int*)carve(sizeof(int) * T_TOK);
  int* rowOf     = (int*)carve(sizeof(int) * T_TOK);
  int* perm      = (int*)carve(sizeof(int) * MCAP);
  int* blockHist = (int*)carve(sizeof(int) * NBLK * NEXP);
  int* blockBase = (int*)carve(sizeof(int) * NBLK * NEXP);
  __hip_bfloat16* Xs   = (__hip_bfloat16*)carve((size_t)MCAP * 128 * 2);
  __hip_bfloat16* actA = (__hip_bfloat16*)carve((size_t)MCAP * 512 * 2);
  __hip_bfloat16* actB = (__hip_bfloat16*)carve((size_t)MCAP * 512 * 2);
  __hip_bfloat16* Wb[7];
  for (int i = 0; i < 7; ++i) Wb[i] = (__hip_bfloat16*)carve((size_t)NEXP * NN[i] * KK[i] * 2);

  k_init<<<dim3((MCAP + 255) / 256), 256, 0, stream>>>(perm);
  for (int i = 0; i < 7; ++i) {
    int n4 = NEXP * NN[i] * KK[i] / 4;
    k_w2bf<<<dim3((n4 + 255) / 256), 256, 0, stream>>>(Wf[i], (unsigned long long*)Wb[i], n4);
  }
  k_hist<<<dim3(NBLK), 256, 0, stream>>>(input, ids, blockHist);
  k_scan<<<dim3(1), 64, 0, stream>>>(blockHist, blockBase, meta);
  k_assign<<<dim3(NBLK), 256, 0, stream>>>(ids, blockBase, rowOf, perm);
  k_gather<<<dim3(T_TOK * 32 / 256), 256, 0, stream>>>(input, rowOf, Xs);
  k_padfill<<<dim3((MCAP + 255) / 256), 256, 0, stream>>>(meta, perm, (unsigned int*)Xs);

  dim3 blk(256);
  k_gemm<128, 64, 128, 512, 2, 2, true,  false><<<dim3(MT_MAX, 4), blk, 0, stream>>>(Xs,   Wb[0], Bf[0], actA, nullptr, meta, perm);
  k_gemm<128, 64, 512, 512, 2, 2, true,  false><<<dim3(MT_MAX, 4), blk, 0, stream>>>(actA, Wb[1], Bf[1], actB, nullptr, meta, perm);
  k_gemm<128, 64, 512, 512, 2, 2, false, false><<<dim3(MT_MAX, 4), blk, 0, stream>>>(actB, Wb[2], Bf[2], actA, nullptr, meta, perm);
  k_gemm<128, 64, 512, 512, 2, 2, true,  false><<<dim3(MT_MAX, 4), blk, 0, stream>>>(actA, Wb[3], Bf[3], actB, nullptr, meta, perm);
  k_gemm<128, 64, 512, 512, 2, 2, true,  false><<<dim3(MT_MAX, 4), blk, 0, stream>>>(actB, Wb[4], Bf[4], actA, nullptr, meta, perm);
  k_gemm<128, 64, 512, 256, 2, 2, false, false><<<dim3(MT_MAX, 2), blk, 0, stream>>>(actA, Wb[5], Bf[5], actB, nullptr, meta, perm);
  k_gemm< 32, 64, 256,  32, 4, 1, false, true ><<<dim3(MT_MAX, 1), blk, 0, stream>>>(actB, Wb[6], Bf[6], nullptr, out, meta, perm);
}

// Round 4
// 205.101 us; speedup vs baseline: 2.6009x; 1.1199x over previous
//
#include <hip/hip_runtime.h>
#include <hip/hip_bf16.h>
#include <stdint.h>

#define T_TOK 32768
#define NEXP 8
#define BMT 128           // M tile
#define MT_MAX 264        // max M tiles incl. per-expert padding
#define MCAP (MT_MAX * BMT)
#define NBLK (T_TOK / 256) // routing blocks
#define SMAX 64           // max M-tiles per expert (8192 tokens; >>13 sigma)

typedef short s16x8 __attribute__((ext_vector_type(8)));
typedef float f32x4 __attribute__((ext_vector_type(4)));

__device__ __forceinline__ void gload_lds16(const void* g, void* l) {
  typedef const __attribute__((address_space(1))) unsigned int gu32;
  typedef __attribute__((address_space(3))) unsigned int lu32;
  __builtin_amdgcn_global_load_lds((gu32*)(unsigned long long)g,
                                   (lu32*)(unsigned int)(unsigned long long)l,
                                   16, 0, 0);
}

// ---------------- routing (atomic-free at device scope) ----------------

__global__ void k_init(int* __restrict__ perm) {
  int i = blockIdx.x * blockDim.x + threadIdx.x;
  if (i < MCAP) perm[i] = -1;
}

__global__ void k_hist(const float* __restrict__ in, int* __restrict__ ids,
                       int* __restrict__ blockHist) {
  __shared__ int h[NEXP];
  int tid = threadIdx.x;
  if (tid < NEXP) h[tid] = 0;
  __syncthreads();
  int t = blockIdx.x * 256 + tid;
  const float* p = in + (size_t)t * 136 + 128;
  float bv = p[0]; int best = 0;
#pragma unroll
  for (int j = 1; j < 8; ++j) { float v = p[j]; if (v > bv) { bv = v; best = j; } }
  ids[t] = best;
  atomicAdd(&h[best], 1);   // LDS atomic — cheap
  __syncthreads();
  if (tid < NEXP) blockHist[blockIdx.x * NEXP + tid] = h[tid];
}

__global__ void k_scan(const int* __restrict__ blockHist, int* __restrict__ blockBase,
                       int* __restrict__ meta) {
  __shared__ int cnt[NEXP];
  int e = threadIdx.x;
  if (e < NEXP) {
    int acc = 0;
    for (int b = 0; b < NBLK; ++b) {
      blockBase[b * NEXP + e] = acc;
      acc += blockHist[b * NEXP + e];
    }
    cnt[e] = acc;
  }
  __syncthreads();
  if (e == 0) {
    int acc = 0;
    for (int i = 0; i < NEXP; ++i) {
      meta[16 + i] = acc;
      acc += ((cnt[i] + BMT - 1) / BMT) * BMT;
    }
    meta[16 + NEXP] = acc;
  }
  __syncthreads();
  if (e < NEXP) {
    int o = meta[16 + e];
    for (int b = 0; b < NBLK; ++b) blockBase[b * NEXP + e] += o;
  }
}

__global__ void k_assign(const int* __restrict__ ids, const int* __restrict__ blockBase,
                         int* __restrict__ rowOf, int* __restrict__ perm) {
  __shared__ int cur[NEXP];
  int tid = threadIdx.x;
  if (tid < NEXP) cur[tid] = blockBase[blockIdx.x * NEXP + tid];
  __syncthreads();
  int t = blockIdx.x * 256 + tid;
  int e = ids[t];
  int row = atomicAdd(&cur[e], 1);   // LDS atomic — cheap
  rowOf[t] = row;
  perm[row] = t;
}

__global__ void k_gather(const float* __restrict__ in, const int* __restrict__ rowOf,
                         __hip_bfloat16* __restrict__ Xs) {
  int g = blockIdx.x * blockDim.x + threadIdx.x;
  if (g >= T_TOK * 32) return;
  int t = g >> 5, c = g & 31;
  int row = rowOf[t];
  f32x4 v = *(const f32x4*)(in + (size_t)t * 136 + c * 4);
  union { unsigned short u[4]; unsigned long long ll; } pk;
#pragma unroll
  for (int j = 0; j < 4; ++j) {
    __hip_bfloat16 h = __float2bfloat16(v[j]);
    pk.u[j] = *(unsigned short*)&h;
  }
  *(unsigned long long*)(Xs + (size_t)row * 128 + c * 4) = pk.ll;
}

__global__ void k_padfill(const int* __restrict__ meta, const int* __restrict__ perm,
                          unsigned int* __restrict__ Xs32) {
  int row = blockIdx.x * blockDim.x + threadIdx.x;
  if (row >= MCAP) return;
  int mtotal = meta[16 + NEXP];
  if (row < mtotal && perm[row] < 0) {
    unsigned int* p = Xs32 + (size_t)row * 64;
#pragma unroll 4
    for (int c = 0; c < 64; ++c) p[c] = 0;
  }
}

__global__ void k_w2bf(const float* __restrict__ s, unsigned long long* __restrict__ d, int n4) {
  int i = blockIdx.x * blockDim.x + threadIdx.x;
  if (i >= n4) return;
  f32x4 v = ((const f32x4*)s)[i];
  union { unsigned short u[4]; unsigned long long ll; } pk;
#pragma unroll
  for (int j = 0; j < 4; ++j) {
    __hip_bfloat16 h = __float2bfloat16(v[j]);
    pk.u[j] = *(unsigned short*)&h;
  }
  d[i] = pk.ll;
}

// ---------------- grouped GEMM (XCD-affinity + dbuf + counted vmcnt + swizzle) ----
// Block mapping: bid = ((s*NY + y) * 8) + e  ->  all blocks of expert e land on
// XCD e (blockIdx round-robins over the 8 XCDs). W[e] stays L2-resident on its
// XCD; A-tiles get L2 reuse across the NY y-blocks. Inactive slots exit early.

template <int BN, int BK, int KT, int NT, int WAVES_M, int WAVES_N, bool RELU, bool FINAL>
__global__ __launch_bounds__(256) void k_gemm(
    const __hip_bfloat16* __restrict__ A,
    const __hip_bfloat16* __restrict__ W,
    const float* __restrict__ bias,
    __hip_bfloat16* __restrict__ Y,
    float* __restrict__ Yf,
    const int* __restrict__ meta,
    const int* __restrict__ perm) {
  static_assert(WAVES_M * WAVES_N == 4, "256 threads = 4 waves");
  constexpr int WTM = BMT / WAVES_M;
  constexpr int WTN = BN / WAVES_N;
  constexpr int FM = WTM / 16, FN = WTN / 16;
  constexpr int CPR = BK / 8;                 // 16B chunks per row (8 for BK=64)
  constexpr int NA = (BMT * BK / 8) / 256;    // A-stage issues per thread
  constexpr int NB = (BN * BK / 8) / 256;     // B-stage issues per thread
  constexpr int NLD = NA + NB;
  constexpr int NSTEP = KT / BK;
  constexpr int NY = NT / BN;

  __shared__ __hip_bfloat16 lA[2][BMT * BK];
  __shared__ __hip_bfloat16 lB[2][BN * BK];

  const int* offp = meta + 16;
  int bid = blockIdx.x;
  int e = bid & 7;
  int rr = bid >> 3;
  int y = rr % NY;
  int s = rr / NY;
  int m0 = offp[e] + s * BMT;
  if (m0 >= offp[e + 1]) return;
  int n0 = y * BN;

  int tid = threadIdx.x;
  int lane = tid & 63;
  int wave = tid >> 6;
  int wm0 = (wave / WAVES_N) * WTM;
  int wn0 = (wave % WAVES_N) * WTN;

  f32x4 acc[FM][FN];
#pragma unroll
  for (int i = 0; i < FM; ++i)
#pragma unroll
    for (int j = 0; j < FN; ++j) {
      acc[i][j][0] = 0.f; acc[i][j][1] = 0.f; acc[i][j][2] = 0.f; acc[i][j][3] = 0.f;
    }

  const __hip_bfloat16* Wb = W + ((size_t)e * NT + n0) * KT;

  // stage K-tile kt into buffer b; LDS dest linear, global source chunk-swizzled
  auto stage = [&](int b, int kt) {
#pragma unroll
    for (int i = 0; i < NA; ++i) {
      int c = i * 256 + tid;
      int r = c / CPR, kc = c % CPR;
      int kcs = kc ^ (r & 7);
      gload_lds16(A + (size_t)(m0 + r) * KT + kt + kcs * 8, (char*)lA[b] + c * 16);
    }
#pragma unroll
    for (int i = 0; i < NB; ++i) {
      int c = i * 256 + tid;
      int r = c / CPR, kc = c % CPR;
      int kcs = kc ^ (r & 7);
      gload_lds16(Wb + (size_t)r * KT + kt + kcs * 8, (char*)lB[b] + c * 16);
    }
  };

  stage(0, 0);
  int cur = 0;
  for (int s2 = 0; s2 < NSTEP; ++s2) {
    __builtin_amdgcn_sched_barrier(0);
    if (s2 + 1 < NSTEP) {
      stage(cur ^ 1, (s2 + 1) * BK);
      asm volatile("s_waitcnt vmcnt(%0)" :: "i"(NLD) : "memory");
    } else {
      asm volatile("s_waitcnt vmcnt(0)" ::: "memory");
    }
    __builtin_amdgcn_s_barrier();
    __builtin_amdgcn_sched_barrier(0);

    __builtin_amdgcn_s_setprio(1);
#pragma unroll
    for (int kk = 0; kk < BK; kk += 32) {
      int cj = (kk >> 3) + (lane >> 4);       // 16B chunk index within row
      s16x8 af[FM], bfr[FN];
#pragma unroll
      for (int i = 0; i < FM; ++i) {
        int ar = wm0 + i * 16 + (lane & 15);
        int js = cj ^ (ar & 7);
        af[i] = *(const s16x8*)(lA[cur] + ar * BK + js * 8);
      }
#pragma unroll
      for (int j = 0; j < FN; ++j) {
        int br = wn0 + j * 16 + (lane & 15);
        int js = cj ^ (br & 7);
        bfr[j] = *(const s16x8*)(lB[cur] + br * BK + js * 8);
      }
#pragma unroll
      for (int i = 0; i < FM; ++i)
#pragma unroll
        for (int j = 0; j < FN; ++j)
          acc[i][j] = __builtin_amdgcn_mfma_f32_16x16x32_bf16(af[i], bfr[j], acc[i][j], 0, 0, 0);
    }
    __builtin_amdgcn_s_setprio(0);
    __builtin_amdgcn_sched_barrier(0);
    __builtin_amdgcn_s_barrier();
    cur ^= 1;
  }

  const float* bp = bias + (size_t)e * NT + n0;
#pragma unroll
  for (int j = 0; j < FN; ++j) {
    int nc = wn0 + j * 16 + (lane & 15);
    float bv = bp[nc];
#pragma unroll
    for (int i = 0; i < FM; ++i) {
#pragma unroll
      for (int r = 0; r < 4; ++r) {
        int mr = wm0 + i * 16 + ((lane >> 4) << 2) + r;
        float v = acc[i][j][r] + bv;
        if (RELU) v = fmaxf(v, 0.f);
        if (FINAL) {
          int tok = perm[m0 + mr];
          if (tok >= 0) Yf[(size_t)tok * NT + n0 + nc] = v;
        } else {
          Y[(size_t)(m0 + mr) * NT + n0 + nc] = __float2bfloat16(v);
        }
      }
    }
  }
}

// ---------------- host ----------------

extern "C" void kernel_launch(void* const* d_in, const int* in_sizes, int n_in,
                              void* d_out, int out_size, void* d_ws, size_t ws_size,
                              hipStream_t stream) {
  const float* input = (const float*)d_in[0];
  const float* Wf[7]; const float* Bf[7];
  for (int i = 0; i < 7; ++i) { Wf[i] = (const float*)d_in[1 + 2 * i]; Bf[i] = (const float*)d_in[2 + 2 * i]; }
  float* out = (float*)d_out;

  static const int NN[7] = {512, 512, 512, 512, 512, 256, 32};
  static const int KK[7] = {128, 512, 512, 512, 512, 512, 256};

  char* ws = (char*)d_ws;
  size_t off = 0;
  auto carve = [&](size_t bytes) {
    void* p = ws + off;
    off = (off + bytes + 255) & ~(size_t)255;
    return p;
  };
  int* meta      = (int*)carve(128);                    // offp at meta[16..24]
  int* ids       = (int*)carve(sizeof(int) * T_TOK);
  int* rowOf     = (int*)carve(sizeof(int) * T_TOK);
  int* perm      = (int*)carve(sizeof(int) * MCAP);
  int* blockHist = (int*)carve(sizeof(int) * NBLK * NEXP);
  int* blockBase = (int*)carve(sizeof(int) * NBLK * NEXP);
  __hip_bfloat16* Xs   = (__hip_bfloat16*)carve((size_t)MCAP * 128 * 2);
  __hip_bfloat16* actA = (__hip_bfloat16*)carve((size_t)MCAP * 512 * 2);
  __hip_bfloat16* actB = (__hip_bfloat16*)carve((size_t)MCAP * 512 * 2);
  __hip_bfloat16* Wb[7];
  for (int i = 0; i < 7; ++i) Wb[i] = (__hip_bfloat16*)carve((size_t)NEXP * NN[i] * KK[i] * 2);

  k_init<<<dim3((MCAP + 255) / 256), 256, 0, stream>>>(perm);
  for (int i = 0; i < 7; ++i) {
    int n4 = NEXP * NN[i] * KK[i] / 4;
    k_w2bf<<<dim3((n4 + 255) / 256), 256, 0, stream>>>(Wf[i], (unsigned long long*)Wb[i], n4);
  }
  k_hist<<<dim3(NBLK), 256, 0, stream>>>(input, ids, blockHist);
  k_scan<<<dim3(1), 64, 0, stream>>>(blockHist, blockBase, meta);
  k_assign<<<dim3(NBLK), 256, 0, stream>>>(ids, blockBase, rowOf, perm);
  k_gather<<<dim3(T_TOK * 32 / 256), 256, 0, stream>>>(input, rowOf, Xs);
  k_padfill<<<dim3((MCAP + 255) / 256), 256, 0, stream>>>(meta, perm, (unsigned int*)Xs);

  dim3 blk(256);
  // grid.x = 8 experts * NY * SMAX slots; bid%8 == expert -> XCD affinity
  k_gemm<128, 64, 128, 512, 2, 2, true,  false><<<dim3(8 * 4 * SMAX), blk, 0, stream>>>(Xs,   Wb[0], Bf[0], actA, nullptr, meta, perm);
  k_gemm<128, 64, 512, 512, 2, 2, true,  false><<<dim3(8 * 4 * SMAX), blk, 0, stream>>>(actA, Wb[1], Bf[1], actB, nullptr, meta, perm);
  k_gemm<128, 64, 512, 512, 2, 2, false, false><<<dim3(8 * 4 * SMAX), blk, 0, stream>>>(actB, Wb[2], Bf[2], actA, nullptr, meta, perm);
  k_gemm<128, 64, 512, 512, 2, 2, true,  false><<<dim3(8 * 4 * SMAX), blk, 0, stream>>>(actA, Wb[3], Bf[3], actB, nullptr, meta, perm);
  k_gemm<128, 64, 512, 512, 2, 2, true,  false><<<dim3(8 * 4 * SMAX), blk, 0, stream>>>(actB, Wb[4], Bf[4], actA, nullptr, meta, perm);
  k_gemm<128, 64, 512, 256, 2, 2, false, false><<<dim3(8 * 2 * SMAX), blk, 0, stream>>>(actA, Wb[5], Bf[5], actB, nullptr, meta, perm);
  k_gemm< 32, 64, 256,  32, 4, 1, false, true ><<<dim3(8 * 1 * SMAX), blk, 0, stream>>>(actB, Wb[6], Bf[6], nullptr, out, meta, perm);
}